// Round 4
// baseline (42.904 us; speedup 1.0000x reference)
//
#include <hip/hip_runtime.h>

#ifndef __has_builtin
#define __has_builtin(x) 0
#endif

#if __has_builtin(__builtin_amdgcn_sdot4)
#define DOT4(a, b, c) __builtin_amdgcn_sdot4((a), (b), (c), false)
#else
__device__ __forceinline__ int dot4_sw(int a, int b, int c) {
#pragma unroll
    for (int k = 0; k < 4; ++k)
        c += (int)(signed char)((a >> (8 * k)) & 0xff) *
             (int)(signed char)((b >> (8 * k)) & 0xff);
    return c;
}
#define DOT4(a, b, c) dot4_sw((a), (b), (c))
#endif

constexpr int CH   = 256;   // channels
constexpr int NPIX = 1024;  // 32*32
constexpr int TW   = 36;    // padded LDS tile dim (32 + 2*2 halo)
constexpr int IMGS = 2;     // images per block
constexpr float BN_EPS = 1e-5f;

// One block per (image-pair, group). 256 threads, each owns 4 consecutive
// pixels of both images. Single barrier; all global loads issued early.
__global__ void bconv_fused(const float* __restrict__ x,
                            const float* __restrict__ wgt,
                            const float* __restrict__ gamma,
                            const float* __restrict__ beta,
                            const float* __restrict__ rmean,
                            const float* __restrict__ rvar,
                            float* __restrict__ out)
{
    __shared__ __align__(16) int TP[IMGS][TW * TW];  // int8x4 over 4 group channels

    const int tid = threadIdx.x;
    const int n0  = (blockIdx.x >> 6) * IMGS;
    const int g   = blockIdx.x & 63;

    const int pix0 = tid * 4;
    const int row  = pix0 >> 5;
    const int col0 = pix0 & 31;

    // Issue conv-input loads for both images first (8 outstanding float4).
    float4 xa[IMGS][4];
#pragma unroll
    for (int i = 0; i < IMGS; ++i)
#pragma unroll
        for (int ci = 0; ci < 4; ++ci) {
            const float* xp = x + ((n0 + i) * CH + g * 4 + ci) * NPIX + pix0;
            xa[i][ci] = *(const float4*)xp;
        }

    // Zero ONLY the 272 border cells of each tile — disjoint from interior
    // writes, so no barrier needed between zeroing and data staging.
#pragma unroll
    for (int it = 0; it < 6; ++it) {
        int idx = tid + it * 256;
        if (idx < TW * TW) {
            int r = idx / TW, c = idx - r * TW;
            if (r < 2 || r >= TW - 2 || c < 2 || c >= TW - 2) {
#pragma unroll
                for (int i = 0; i < IMGS; ++i) TP[i][idx] = 0;
            }
        }
    }

    // Binarized weights (block-uniform): wq[c2][tap], one int8 lane per ci.
    const float* wp = wgt + g * 144;
    int wq[4][9];
#pragma unroll
    for (int c2 = 0; c2 < 4; ++c2)
#pragma unroll
        for (int t = 0; t < 9; ++t) {
            int pk = 0;
#pragma unroll
            for (int ci = 0; ci < 4; ++ci) {
                float wv = wp[c2 * 36 + ci * 9 + t];
                int s = (wv > 0.f) ? 1 : ((wv < 0.f) ? -1 : 0);
                pk |= (s & 0xff) << (8 * ci);
            }
            wq[c2][t] = pk;
        }

    // BN constants (channel-only, shared by both images). Exact numpy order:
    // inv = gamma * (1/sqrt(var+eps)); bias = beta - mean*inv; no FMA.
    float inv[4], bias[4];
#pragma unroll
    for (int ci = 0; ci < 4; ++ci) {
        const int c = g * 4 + ci;
        float r  = __fdiv_rn(1.0f, __fsqrt_rn(__fadd_rn(rvar[c], BN_EPS)));
        inv[ci]  = __fmul_rn(gamma[c], r);
        bias[ci] = __fsub_rn(beta[c], __fmul_rn(rmean[c], inv[ci]));
    }

    // BN + binarize + pack + stage to LDS (both images).
#pragma unroll
    for (int i = 0; i < IMGS; ++i) {
        int pk[4];
#pragma unroll
        for (int p = 0; p < 4; ++p) {
            int v = 0;
#pragma unroll
            for (int ci = 0; ci < 4; ++ci) {
                float h = __fadd_rn(__fmul_rn(((const float*)&xa[i][ci])[p], inv[ci]), bias[ci]);
                int s = (h > 0.f) ? 1 : ((h < 0.f) ? -1 : 0);
                v |= (s & 0xff) << (8 * ci);
            }
            pk[p] = v;
        }
        const int idx = (row + 2) * TW + (col0 + 2);
        *(int2*)&TP[i][idx]     = make_int2(pk[0], pk[1]);
        *(int2*)&TP[i][idx + 2] = make_int2(pk[2], pk[3]);
    }

    // Issue shortcut loads BEFORE the barrier — latency hides under
    // barrier + LDS reads + dot4 compute.
    float4 sc[IMGS][4];
#pragma unroll
    for (int i = 0; i < IMGS; ++i)
#pragma unroll
        for (int c2 = 0; c2 < 4; ++c2) {
            const int co = c2 * 64 + g;  // channel shuffle target
            sc[i][c2] = *(const float4*)(x + ((n0 + i) * CH + co) * NPIX + pix0);
        }

    __syncthreads();  // the only barrier

    // Conv + shuffle + shortcut + store, per image.
#pragma unroll
    for (int i = 0; i < IMGS; ++i) {
        int a[3][8];
#pragma unroll
        for (int kh = 0; kh < 3; ++kh) {
            const int base = (row + 2 * kh) * TW + col0;  // 16B aligned
            int4 lo = *(const int4*)&TP[i][base];
            int4 hi = *(const int4*)&TP[i][base + 4];
            a[kh][0] = lo.x; a[kh][1] = lo.y; a[kh][2] = lo.z; a[kh][3] = lo.w;
            a[kh][4] = hi.x; a[kh][5] = hi.y; a[kh][6] = hi.z; a[kh][7] = hi.w;
        }
#pragma unroll
        for (int c2 = 0; c2 < 4; ++c2) {
            const int co = c2 * 64 + g;
            float4 o;
#pragma unroll
            for (int p = 0; p < 4; ++p) {
                int acc = 0;
#pragma unroll
                for (int kh = 0; kh < 3; ++kh)
#pragma unroll
                    for (int kw = 0; kw < 3; ++kw)
                        acc = DOT4(a[kh][p + 2 * kw], wq[c2][kh * 3 + kw], acc);
                ((float*)&o)[p] = __fadd_rn((float)acc, ((const float*)&sc[i][c2])[p]);
            }
            *(float4*)(out + ((n0 + i) * CH + co) * NPIX + pix0) = o;
        }
    }
}

extern "C" void kernel_launch(void* const* d_in, const int* in_sizes, int n_in,
                              void* d_out, int out_size, void* d_ws, size_t ws_size,
                              hipStream_t stream) {
    const float* x     = (const float*)d_in[0];
    const float* wgt   = (const float*)d_in[1];
    const float* gamma = (const float*)d_in[2];
    const float* beta  = (const float*)d_in[3];
    const float* rmean = (const float*)d_in[4];
    const float* rvar  = (const float*)d_in[5];
    float* out = (float*)d_out;

    const int N = in_sizes[0] / (CH * NPIX);  // 64
    dim3 grid((N / IMGS) * 64);               // 2048 blocks = 8/CU, one round
    bconv_fused<<<grid, 256, 0, stream>>>(x, wgt, gamma, beta, rmean, rvar, out);
}

// Round 6
// 38.382 us; speedup vs baseline: 1.1178x; 1.1178x over previous
//
#include <hip/hip_runtime.h>

#ifndef __has_builtin
#define __has_builtin(x) 0
#endif

#if __has_builtin(__builtin_amdgcn_sdot4)
#define DOT4(a, b, c) __builtin_amdgcn_sdot4((a), (b), (c), false)
#else
__device__ __forceinline__ int dot4_sw(int a, int b, int c) {
#pragma unroll
    for (int k = 0; k < 4; ++k)
        c += (int)(signed char)((a >> (8 * k)) & 0xff) *
             (int)(signed char)((b >> (8 * k)) & 0xff);
    return c;
}
#define DOT4(a, b, c) dot4_sw((a), (b), (c))
#endif

constexpr int CH   = 256;
constexpr int NPIX = 1024;            // 32*32
constexpr int WS_WQ_INTS = 256 * 9;   // packed weights: pair (g*4+c2) major, 9 taps
constexpr float BN_EPS = 1e-5f;

// ---- pre-kernel: pack weights + BN constants into d_ws (runs every call) ----
// block 0: thread c -> inv[c], bias[c]  (exact numpy op order, no FMA)
// blocks 1..9: tap t = blockIdx-1; thread p = output channel (g*4+c2):
//              pack 4 input-channel weight signs into one int8x4.
__global__ void prepack(const float* __restrict__ wgt,
                        const float* __restrict__ gamma,
                        const float* __restrict__ beta,
                        const float* __restrict__ rmean,
                        const float* __restrict__ rvar,
                        int* __restrict__ wsw, float* __restrict__ wsb) {
    const int tid = threadIdx.x;
    if (blockIdx.x == 0) {
        float r  = __fdiv_rn(1.0f, __fsqrt_rn(__fadd_rn(rvar[tid], BN_EPS)));
        float iv = __fmul_rn(gamma[tid], r);
        wsb[tid]       = iv;
        wsb[256 + tid] = __fsub_rn(beta[tid], __fmul_rn(rmean[tid], iv));
    } else {
        const int t = blockIdx.x - 1;          // tap 0..8
        const float* wp = wgt + tid * 36;      // [co][ci][3][3], co = tid
        int pk = 0;
#pragma unroll
        for (int ci = 0; ci < 4; ++ci) {
            float wv = wp[ci * 9 + t];
            int s = (wv > 0.f) ? 1 : ((wv < 0.f) ? -1 : 0);
            pk |= (s & 0xff) << (8 * ci);
        }
        wsw[tid * 9 + t] = pk;
    }
}

// ---- main kernel: barrier-free, LDS-free. One block per (n, group). ----
// Each thread owns 4 consecutive pixels of one row; loads rows r-2,r,r+2
// itself (clamped addr + masked result), packs signs, gets lateral halo
// (cols +-2) from lane+-1 via shuffle (8 lanes per row), then 144 dot4.
__global__ __launch_bounds__(256) void bconv(const float* __restrict__ x,
                                             const int* __restrict__ wsw,
                                             const float* __restrict__ wsb,
                                             float* __restrict__ out) {
    const int tid  = threadIdx.x;
    const int n    = blockIdx.x >> 6;
    const int g    = blockIdx.x & 63;
    const int pix0 = tid * 4;
    const int row  = pix0 >> 5;
    const int col0 = pix0 & 31;
    const float* xn = x + n * CH * NPIX;
    float* on = out + n * CH * NPIX;

    // uniform scalars (s_load): packed weights + BN consts
    int wq[4][9];
    const int* wqp = wsw + g * 36;
#pragma unroll
    for (int c2 = 0; c2 < 4; ++c2)
#pragma unroll
        for (int t = 0; t < 9; ++t) wq[c2][t] = wqp[c2 * 9 + t];
    float inv[4], bias[4];
#pragma unroll
    for (int ci = 0; ci < 4; ++ci) {
        inv[ci]  = wsb[g * 4 + ci];
        bias[ci] = wsb[256 + g * 4 + ci];
    }

    // issue ALL global loads upfront: 4 shortcut + 12 conv-input float4
    float4 sc[4];
#pragma unroll
    for (int c2 = 0; c2 < 4; ++c2)
        sc[c2] = *(const float4*)(xn + (c2 * 64 + g) * NPIX + pix0);

    float4 xv[3][4];
#pragma unroll
    for (int kh = 0; kh < 3; ++kh) {
        const int rs  = row + 2 * kh - 2;
        const int rsc = min(max(rs, 0), 31);   // clamp addr; mask result below
        const float* rp = xn + g * 4 * NPIX + rsc * 32 + col0;
#pragma unroll
        for (int ci = 0; ci < 4; ++ci)
            xv[kh][ci] = *(const float4*)(rp + ci * NPIX);
    }

    // BN + sign + pack int8x4 over ci; zero packed value for out-of-range rows
    int pkc[3][4];
#pragma unroll
    for (int kh = 0; kh < 3; ++kh) {
        const bool ok = (unsigned)(row + 2 * kh - 2) < 32u;
#pragma unroll
        for (int p = 0; p < 4; ++p) {
            int v = 0;
#pragma unroll
            for (int ci = 0; ci < 4; ++ci) {
                float h = __fadd_rn(__fmul_rn(((const float*)&xv[kh][ci])[p], inv[ci]), bias[ci]);
                int s = (h > 0.f) ? 1 : ((h < 0.f) ? -1 : 0);
                v |= (s & 0xff) << (8 * ci);
            }
            pkc[kh][p] = ok ? v : 0;
        }
    }

    // lateral halo: cols col0-2,col0-1 from lane-1; col0+4,col0+5 from lane+1.
    // 8 lanes per row, so row-edge lanes are exactly col-edge lanes (masked).
    const bool le = (col0 == 0), re = (col0 == 28);
    int a[3][8];
#pragma unroll
    for (int kh = 0; kh < 3; ++kh) {
        int l2 = __shfl_up(pkc[kh][2], 1);
        int l3 = __shfl_up(pkc[kh][3], 1);
        int r0 = __shfl_down(pkc[kh][0], 1);
        int r1 = __shfl_down(pkc[kh][1], 1);
        a[kh][0] = le ? 0 : l2;
        a[kh][1] = le ? 0 : l3;
        a[kh][2] = pkc[kh][0]; a[kh][3] = pkc[kh][1];
        a[kh][4] = pkc[kh][2]; a[kh][5] = pkc[kh][3];
        a[kh][6] = re ? 0 : r0;
        a[kh][7] = re ? 0 : r1;
    }

    // conv + channel shuffle + shortcut + store
#pragma unroll
    for (int c2 = 0; c2 < 4; ++c2) {
        float4 o;
#pragma unroll
        for (int p = 0; p < 4; ++p) {
            int acc = 0;
#pragma unroll
            for (int kh = 0; kh < 3; ++kh)
#pragma unroll
                for (int kw = 0; kw < 3; ++kw)
                    acc = DOT4(a[kh][p + 2 * kw], wq[c2][kh * 3 + kw], acc);
            ((float*)&o)[p] = __fadd_rn((float)acc, ((const float*)&sc[c2])[p]);
        }
        *(float4*)(on + (c2 * 64 + g) * NPIX + pix0) = o;
    }
}

extern "C" void kernel_launch(void* const* d_in, const int* in_sizes, int n_in,
                              void* d_out, int out_size, void* d_ws, size_t ws_size,
                              hipStream_t stream) {
    const float* x     = (const float*)d_in[0];
    const float* wgt   = (const float*)d_in[1];
    const float* gamma = (const float*)d_in[2];
    const float* beta  = (const float*)d_in[3];
    const float* rmean = (const float*)d_in[4];
    const float* rvar  = (const float*)d_in[5];
    float* out = (float*)d_out;

    int*   wsw = (int*)d_ws;                                  // 9216 B
    float* wsb = (float*)((char*)d_ws + WS_WQ_INTS * 4);      // + 2048 B

    prepack<<<10, 256, 0, stream>>>(wgt, gamma, beta, rmean, rvar, wsw, wsb);

    const int N = in_sizes[0] / (CH * NPIX);  // 64
    bconv<<<N * 64, 256, 0, stream>>>(x, wsw, wsb, out);
}

// Round 7
// 34.586 us; speedup vs baseline: 1.2405x; 1.1097x over previous
//
#include <hip/hip_runtime.h>

#ifndef __has_builtin
#define __has_builtin(x) 0
#endif

#if __has_builtin(__builtin_amdgcn_sdot4)
#define DOT4(a, b, c) __builtin_amdgcn_sdot4((a), (b), (c), false)
#else
__device__ __forceinline__ int dot4_sw(int a, int b, int c) {
#pragma unroll
    for (int k = 0; k < 4; ++k)
        c += (int)(signed char)((a >> (8 * k)) & 0xff) *
             (int)(signed char)((b >> (8 * k)) & 0xff);
    return c;
}
#define DOT4(a, b, c) dot4_sw((a), (b), (c))
#endif

constexpr int CH   = 256;
constexpr int NPIX = 1024;   // 32*32
constexpr float BN_EPS = 1e-5f;

__device__ __forceinline__ float rfl_f(float v) {
    return __int_as_float(__builtin_amdgcn_readfirstlane(__float_as_int(v)));
}

// Single fused kernel. One block per (n, group); 256 threads, 4 px each.
// Lanes 0..143 pack one weight sign-byte into LDS; lanes 144..147 compute BN
// consts; one barrier; uniform state pulled to SGPRs via readfirstlane.
// Main path is barrier-free per-thread: direct row loads (clamped+masked),
// lateral halo via lane shuffles, 144 sdot4, fused shuffle+shortcut store.
__global__ __launch_bounds__(256) void bconv(const float* __restrict__ x,
                                             const float* __restrict__ wgt,
                                             const float* __restrict__ gamma,
                                             const float* __restrict__ beta,
                                             const float* __restrict__ rmean,
                                             const float* __restrict__ rvar,
                                             float* __restrict__ out) {
    __shared__ int   wq_lds[36];   // int8x4 over ci, indexed [c2*9+tap]
    __shared__ float bn_lds[8];    // inv[4], bias[4]

    const int tid  = threadIdx.x;
    const int n    = blockIdx.x >> 6;
    const int g    = blockIdx.x & 63;
    const int pix0 = tid * 4;
    const int row  = pix0 >> 5;
    const int col0 = pix0 & 31;
    const float* xn = x + n * CH * NPIX;
    float* on = out + n * CH * NPIX;

    // ---- issue ALL 16 big loads first (12 conv-input + 4 shortcut) ----
    float4 xv[3][4];
#pragma unroll
    for (int kh = 0; kh < 3; ++kh) {
        const int rs  = row + 2 * kh - 2;
        const int rsc = min(max(rs, 0), 31);   // clamp addr; mask result later
        const float* rp = xn + g * 4 * NPIX + rsc * 32 + col0;
#pragma unroll
        for (int ci = 0; ci < 4; ++ci)
            xv[kh][ci] = *(const float4*)(rp + ci * NPIX);
    }
    float4 sc[4];
#pragma unroll
    for (int c2 = 0; c2 < 4; ++c2)
        sc[c2] = *(const float4*)(xn + (c2 * 64 + g) * NPIX + pix0);

    // ---- in-block prep: weights (144 lanes) + BN consts (4 lanes) ----
    if (tid < 144) {
        const int c2 = tid / 36, r = tid % 36, ci = r / 9, tap = r % 9;
        float w = wgt[g * 144 + tid];   // [co][ci][3][3], co = g*4+c2
        int s = (w > 0.f) ? 1 : ((w < 0.f) ? -1 : 0);
        ((char*)wq_lds)[(c2 * 9 + tap) * 4 + ci] = (char)s;
    } else if (tid < 148) {
        const int ci = tid - 144, c = g * 4 + ci;
        float r  = __fdiv_rn(1.0f, __fsqrt_rn(__fadd_rn(rvar[c], BN_EPS)));
        float iv = __fmul_rn(gamma[c], r);
        bn_lds[ci]     = iv;
        bn_lds[4 + ci] = __fsub_rn(beta[c], __fmul_rn(rmean[c], iv));
    }
    __syncthreads();   // drain == the xv wait we need immediately anyway

    // uniform state -> SGPRs (readfirstlane; LDS reads are broadcasts)
    int wq[4][9];
#pragma unroll
    for (int c2 = 0; c2 < 4; ++c2)
#pragma unroll
        for (int t = 0; t < 9; ++t)
            wq[c2][t] = __builtin_amdgcn_readfirstlane(wq_lds[c2 * 9 + t]);
    float inv[4], bias[4];
#pragma unroll
    for (int ci = 0; ci < 4; ++ci) {
        inv[ci]  = rfl_f(bn_lds[ci]);
        bias[ci] = rfl_f(bn_lds[4 + ci]);
    }

    // ---- BN + sign + pack int8x4 over ci; zero out-of-range rows ----
    int pkc[3][4];
#pragma unroll
    for (int kh = 0; kh < 3; ++kh) {
        const bool ok = (unsigned)(row + 2 * kh - 2) < 32u;
#pragma unroll
        for (int p = 0; p < 4; ++p) {
            int v = 0;
#pragma unroll
            for (int ci = 0; ci < 4; ++ci) {
                float h = __fadd_rn(__fmul_rn(((const float*)&xv[kh][ci])[p], inv[ci]), bias[ci]);
                int s = (h > 0.f) ? 1 : ((h < 0.f) ? -1 : 0);
                v |= (s & 0xff) << (8 * ci);
            }
            pkc[kh][p] = ok ? v : 0;
        }
    }

    // ---- lateral halo from lane+-1 (8 lanes per row; edges masked) ----
    const bool le = (col0 == 0), re = (col0 == 28);
    int a[3][8];
#pragma unroll
    for (int kh = 0; kh < 3; ++kh) {
        int l2 = __shfl_up(pkc[kh][2], 1);
        int l3 = __shfl_up(pkc[kh][3], 1);
        int r0 = __shfl_down(pkc[kh][0], 1);
        int r1 = __shfl_down(pkc[kh][1], 1);
        a[kh][0] = le ? 0 : l2;
        a[kh][1] = le ? 0 : l3;
        a[kh][2] = pkc[kh][0]; a[kh][3] = pkc[kh][1];
        a[kh][4] = pkc[kh][2]; a[kh][5] = pkc[kh][3];
        a[kh][6] = re ? 0 : r0;
        a[kh][7] = re ? 0 : r1;
    }

    // ---- conv + channel shuffle + shortcut + store ----
#pragma unroll
    for (int c2 = 0; c2 < 4; ++c2) {
        float4 o;
#pragma unroll
        for (int p = 0; p < 4; ++p) {
            int acc = 0;
#pragma unroll
            for (int kh = 0; kh < 3; ++kh)
#pragma unroll
                for (int kw = 0; kw < 3; ++kw)
                    acc = DOT4(a[kh][p + 2 * kw], wq[c2][kh * 3 + kw], acc);
            ((float*)&o)[p] = __fadd_rn((float)acc, ((const float*)&sc[c2])[p]);
        }
        *(float4*)(on + (c2 * 64 + g) * NPIX + pix0) = o;
    }
}

extern "C" void kernel_launch(void* const* d_in, const int* in_sizes, int n_in,
                              void* d_out, int out_size, void* d_ws, size_t ws_size,
                              hipStream_t stream) {
    const float* x     = (const float*)d_in[0];
    const float* wgt   = (const float*)d_in[1];
    const float* gamma = (const float*)d_in[2];
    const float* beta  = (const float*)d_in[3];
    const float* rmean = (const float*)d_in[4];
    const float* rvar  = (const float*)d_in[5];
    float* out = (float*)d_out;

    const int N = in_sizes[0] / (CH * NPIX);  // 64
    bconv<<<N * 64, 256, 0, stream>>>(x, wgt, gamma, beta, rmean, rvar, out);
}

// Round 8
// 33.774 us; speedup vs baseline: 1.2703x; 1.0240x over previous
//
#include <hip/hip_runtime.h>

#ifndef __has_builtin
#define __has_builtin(x) 0
#endif

#if __has_builtin(__builtin_amdgcn_sdot4)
#define DOT4(a, b, c) __builtin_amdgcn_sdot4((a), (b), (c), false)
#else
__device__ __forceinline__ int dot4_sw(int a, int b, int c) {
#pragma unroll
    for (int k = 0; k < 4; ++k)
        c += (int)(signed char)((a >> (8 * k)) & 0xff) *
             (int)(signed char)((b >> (8 * k)) & 0xff);
    return c;
}
#define DOT4(a, b, c) dot4_sw((a), (b), (c))
#endif

constexpr int CH   = 256;
constexpr int NPIX = 1024;   // 32*32
constexpr float BN_EPS = 1e-5f;

__device__ __forceinline__ float rfl_f(float v) {
    return __int_as_float(__builtin_amdgcn_readfirstlane(__float_as_int(v)));
}

// One block per (image-pair, group); 256 threads, 4 px each, 2 images.
// Weight/BN setup + barrier once per block (images share the group).
// Software pipeline: pack-A -> issue B loads -> compute/store-A -> pack-B.
__global__ __launch_bounds__(256, 4)
void bconv(const float* __restrict__ x,
           const float* __restrict__ wgt,
           const float* __restrict__ gamma,
           const float* __restrict__ beta,
           const float* __restrict__ rmean,
           const float* __restrict__ rvar,
           float* __restrict__ out) {
    __shared__ int   wq_lds[36];   // int8x4 over ci, [c2*9+tap]
    __shared__ float bn_lds[8];    // inv[4], bias[4]

    const int tid  = threadIdx.x;
    const int n0   = (blockIdx.x >> 6) * 2;
    const int g    = blockIdx.x & 63;
    const int pix0 = tid * 4;
    const int row  = pix0 >> 5;
    const int col0 = pix0 & 31;
    const float* xnA = x + n0 * CH * NPIX;
    const float* xnB = xnA + CH * NPIX;
    float* onA = out + n0 * CH * NPIX;
    float* onB = onA + CH * NPIX;

    float4 xv[3][4];   // reused for A then B
    auto load_xv = [&](const float* xn) {
#pragma unroll
        for (int kh = 0; kh < 3; ++kh) {
            const int rs  = row + 2 * kh - 2;
            const int rsc = min(max(rs, 0), 31);   // clamp addr; mask later
            const float* rp = xn + g * 4 * NPIX + rsc * 32 + col0;
#pragma unroll
            for (int ci = 0; ci < 4; ++ci)
                xv[kh][ci] = *(const float4*)(rp + ci * NPIX);
        }
    };

    // ---- image A loads first ----
    load_xv(xnA);
    float4 scA[4];
#pragma unroll
    for (int c2 = 0; c2 < 4; ++c2)
        scA[c2] = *(const float4*)(xnA + (c2 * 64 + g) * NPIX + pix0);

    // ---- weight pack (144 lanes) + BN consts (4 lanes), once per block ----
    if (tid < 144) {
        const int c2 = tid / 36, r = tid % 36, ci = r / 9, tap = r % 9;
        float w = wgt[g * 144 + tid];   // [co][ci][3][3], co = g*4+c2
        int s = (w > 0.f) ? 1 : ((w < 0.f) ? -1 : 0);
        ((char*)wq_lds)[(c2 * 9 + tap) * 4 + ci] = (char)s;
    } else if (tid < 148) {
        const int ci = tid - 144, c = g * 4 + ci;
        float r  = __fdiv_rn(1.0f, __fsqrt_rn(__fadd_rn(rvar[c], BN_EPS)));
        float iv = __fmul_rn(gamma[c], r);
        bn_lds[ci]     = iv;
        bn_lds[4 + ci] = __fsub_rn(beta[c], __fmul_rn(rmean[c], iv));
    }
    __syncthreads();

    // uniform state -> SGPRs
    int wq[4][9];
#pragma unroll
    for (int c2 = 0; c2 < 4; ++c2)
#pragma unroll
        for (int t = 0; t < 9; ++t)
            wq[c2][t] = __builtin_amdgcn_readfirstlane(wq_lds[c2 * 9 + t]);
    float inv[4], bias[4];
#pragma unroll
    for (int ci = 0; ci < 4; ++ci) {
        inv[ci]  = rfl_f(bn_lds[ci]);
        bias[ci] = rfl_f(bn_lds[4 + ci]);
    }

    // BN + sign + pack int8x4 over ci; zero out-of-range rows
    auto pack = [&](int pkc[3][4]) {
#pragma unroll
        for (int kh = 0; kh < 3; ++kh) {
            const bool ok = (unsigned)(row + 2 * kh - 2) < 32u;
#pragma unroll
            for (int p = 0; p < 4; ++p) {
                int v = 0;
#pragma unroll
                for (int ci = 0; ci < 4; ++ci) {
                    float h = __fadd_rn(__fmul_rn(((const float*)&xv[kh][ci])[p], inv[ci]), bias[ci]);
                    int s = (h > 0.f) ? 1 : ((h < 0.f) ? -1 : 0);
                    v |= (s & 0xff) << (8 * ci);
                }
                pkc[kh][p] = ok ? v : 0;
            }
        }
    };

    const bool le = (col0 == 0), re = (col0 == 28);
    // halo from lane+-1, 144 dot4, + shortcut, store
    auto compute_store = [&](const int pkc[3][4], const float4 sc[4], float* on) {
        int a[3][8];
#pragma unroll
        for (int kh = 0; kh < 3; ++kh) {
            int l2 = __shfl_up(pkc[kh][2], 1);
            int l3 = __shfl_up(pkc[kh][3], 1);
            int r0 = __shfl_down(pkc[kh][0], 1);
            int r1 = __shfl_down(pkc[kh][1], 1);
            a[kh][0] = le ? 0 : l2;
            a[kh][1] = le ? 0 : l3;
            a[kh][2] = pkc[kh][0]; a[kh][3] = pkc[kh][1];
            a[kh][4] = pkc[kh][2]; a[kh][5] = pkc[kh][3];
            a[kh][6] = re ? 0 : r0;
            a[kh][7] = re ? 0 : r1;
        }
#pragma unroll
        for (int c2 = 0; c2 < 4; ++c2) {
            float4 o;
#pragma unroll
            for (int p = 0; p < 4; ++p) {
                int acc = 0;
#pragma unroll
                for (int kh = 0; kh < 3; ++kh)
#pragma unroll
                    for (int kw = 0; kw < 3; ++kw)
                        acc = DOT4(a[kh][p + 2 * kw], wq[c2][kh * 3 + kw], acc);
                ((float*)&o)[p] = __fadd_rn((float)acc, ((const float*)&sc[c2])[p]);
            }
            *(float4*)(on + (c2 * 64 + g) * NPIX + pix0) = o;
        }
    };

    // ---- pipeline: pack A | issue B loads | compute A | pack B | compute B ----
    int pkcA[3][4];
    pack(pkcA);            // waits on xv-A

    load_xv(xnB);          // B conv loads in flight under A compute

    compute_store(pkcA, scA, onA);

    int pkcB[3][4];
    pack(pkcB);            // waits on xv-B

    float4 scB[4];
#pragma unroll
    for (int c2 = 0; c2 < 4; ++c2)
        scB[c2] = *(const float4*)(xnB + (c2 * 64 + g) * NPIX + pix0);

    compute_store(pkcB, scB, onB);
}

extern "C" void kernel_launch(void* const* d_in, const int* in_sizes, int n_in,
                              void* d_out, int out_size, void* d_ws, size_t ws_size,
                              hipStream_t stream) {
    const float* x     = (const float*)d_in[0];
    const float* wgt   = (const float*)d_in[1];
    const float* gamma = (const float*)d_in[2];
    const float* beta  = (const float*)d_in[3];
    const float* rmean = (const float*)d_in[4];
    const float* rvar  = (const float*)d_in[5];
    float* out = (float*)d_out;

    const int N = in_sizes[0] / (CH * NPIX);  // 64
    bconv<<<(N / 2) * 64, 256, 0, stream>>>(x, wgt, gamma, beta, rmean, rvar, out);
}